// Round 14
// baseline (266.897 us; speedup 1.0000x reference)
//
#include <hip/hip_runtime.h>
#include <hip/hip_cooperative_groups.h>
#include <math.h>

namespace cg = cooperative_groups;

#define FEAT 64
#define NB   1024      // cooperative grid: 4 blocks/CU target

typedef float f32x4 __attribute__((ext_vector_type(4)));
typedef int   i32x4 __attribute__((ext_vector_type(4)));

// dequant-accumulate one packed word (4 biased-uint8 feats) into acc.
// (float)(u & 255) folds to v_cvt_f32_ubyte{0..3}.
__device__ __forceinline__ void dq_acc(int p, float wk, f32x4& acc) {
    unsigned up = (unsigned)p;
    acc.x = fmaf(wk, (float)(up & 255u),         acc.x);
    acc.y = fmaf(wk, (float)((up >> 8) & 255u),  acc.y);
    acc.z = fmaf(wk, (float)((up >> 16) & 255u), acc.z);
    acc.w = fmaf(wk, (float)(up >> 24),          acc.w);
}

// ---- quant body: rows rbase_g + 4i, i=0..3 (call with rbase_g = 16*wave + g,
// g = lane>>4, so one wave covers rows 16w..16w+15 — R10-proven mapping) ----
__device__ __forceinline__ void quant_rows16(
    const float* __restrict__ values, int* __restrict__ vq,
    float* __restrict__ scale, int num_rows, int rbase_g, int f4)
{
    f32x4 v[4];
    #pragma unroll
    for (int i = 0; i < 4; ++i) {
        const int row = rbase_g + (i << 2);
        v[i] = (f32x4){0.0f, 0.0f, 0.0f, 0.0f};
        if (row < num_rows)
            v[i] = __builtin_nontemporal_load(
                       (const f32x4*)(values + (long long)row * FEAT) + f4);
    }
    #pragma unroll
    for (int i = 0; i < 4; ++i) {
        const int row = rbase_g + (i << 2);
        float a = fmaxf(fmaxf(fabsf(v[i].x), fabsf(v[i].y)),
                        fmaxf(fabsf(v[i].z), fabsf(v[i].w)));
        a = fmaxf(a, __shfl_xor(a, 1));
        a = fmaxf(a, __shfl_xor(a, 2));
        a = fmaxf(a, __shfl_xor(a, 4));
        a = fmaxf(a, __shfl_xor(a, 8));
        if (row < num_rows) {
            const float inv = (a > 0.0f) ? 127.0f / a : 0.0f;
            int q0 = (int)rintf(v[i].x * inv) + 128;
            int q1 = (int)rintf(v[i].y * inv) + 128;
            int q2 = (int)rintf(v[i].z * inv) + 128;
            int q3 = (int)rintf(v[i].w * inv) + 128;
            // plain store: d_ws is device-consumed (R5 poison lesson)
            vq[((unsigned)row << 4) + f4] = q0 | (q1 << 8) | (q2 << 16) | (q3 << 24);
            if (f4 == 0) scale[row] = a * (1.0f / 127.0f);
        }
    }
}

// generic per-node fallback (any degree, either index width, fp32 values)
__device__ __noinline__ void node_generic(
    const void* row_ptr_v, const void* col_idx_v, const float* scores,
    const float* values, float* out, int node, int lane, bool idx64)
{
    const int* rp32 = (const int*)row_ptr_v;
    long long start, end;
    if (idx64) {
        const long long* rp = (const long long*)row_ptr_v;
        start = rp[node]; end = rp[node + 1];
    } else {
        start = (long long)rp32[node]; end = (long long)rp32[node + 1];
    }
    float m = -INFINITY;
    for (long long e = start; e < end; ++e) m = fmaxf(m, scores[e]);
    float sum = 0.0f;
    for (long long e = start; e < end; ++e) sum += __expf(scores[e] - m);
    const float invs = (sum > 0.0f) ? 1.0f / sum : 0.0f;
    float acc = 0.0f;
    for (long long e = start; e < end; ++e) {
        long long c = idx64 ? ((const long long*)col_idx_v)[e]
                            : (long long)((const int*)col_idx_v)[e];
        acc += __expf(scores[e] - m) * values[c * FEAT + lane];
    }
    out[(long long)node * FEAT + lane] = acc * invs;
}

// ---- main body: one node PAIR (R10-proven, byte-identical math) ----
__device__ __forceinline__ void pair_body(
    const int* __restrict__ rp32,
    const void* __restrict__ row_ptr_v,
    const void* __restrict__ col_idx_v,
    const float* __restrict__ scores,
    const int* __restrict__ vq,
    const float* __restrict__ scale,
    const float* __restrict__ values,
    float* __restrict__ out,
    int num_nodes, long long num_edges, bool idx64,
    int wid0, int lane, int q, int f4)
{
    const long long base = (long long)wid0 * 16;
    const bool inb = (wid0 + 2 <= num_nodes) && (base + 32 <= num_edges);

    if (inb && !idx64) {
        const int b16 = wid0 * 16;
        const int r0 = rp32[wid0], r1 = rp32[wid0 + 1], r2 = rp32[wid0 + 2];

        const float* sb = scores + base;
        const int*   cb = (const int*)col_idx_v + base;
        f32x4 sv0 = __builtin_nontemporal_load((const f32x4*)sb + q);
        f32x4 sv1 = __builtin_nontemporal_load((const f32x4*)(sb + 16) + q);
        i32x4 cv0 = __builtin_nontemporal_load((const i32x4*)cb + q);
        i32x4 cv1 = __builtin_nontemporal_load((const i32x4*)(cb + 16) + q);

        // speculative: all 8 row gathers + 8 scale loads before uni resolves
        int p00 = vq[((unsigned)cv0.x << 4) + f4];
        int p01 = vq[((unsigned)cv0.y << 4) + f4];
        int p02 = vq[((unsigned)cv0.z << 4) + f4];
        int p03 = vq[((unsigned)cv0.w << 4) + f4];
        int p10 = vq[((unsigned)cv1.x << 4) + f4];
        int p11 = vq[((unsigned)cv1.y << 4) + f4];
        int p12 = vq[((unsigned)cv1.z << 4) + f4];
        int p13 = vq[((unsigned)cv1.w << 4) + f4];
        float s00 = scale[cv0.x], s01 = scale[cv0.y];
        float s02 = scale[cv0.z], s03 = scale[cv0.w];
        float s10 = scale[cv1.x], s11 = scale[cv1.y];
        float s12 = scale[cv1.z], s13 = scale[cv1.w];

        const bool uni = (r0 == b16) && (r1 == b16 + 16) && (r2 == b16 + 32);
        if (uni) {
            float m0 = fmaxf(fmaxf(sv0.x, sv0.y), fmaxf(sv0.z, sv0.w));
            m0 = fmaxf(m0, __shfl_xor(m0, 16));
            m0 = fmaxf(m0, __shfl_xor(m0, 32));
            float w00 = __expf(sv0.x - m0), w01 = __expf(sv0.y - m0);
            float w02 = __expf(sv0.z - m0), w03 = __expf(sv0.w - m0);
            float t0 = w00 + w01 + w02 + w03;
            t0 += __shfl_xor(t0, 16);
            t0 += __shfl_xor(t0, 32);
            const float inv0 = 1.0f / t0;

            float m1 = fmaxf(fmaxf(sv1.x, sv1.y), fmaxf(sv1.z, sv1.w));
            m1 = fmaxf(m1, __shfl_xor(m1, 16));
            m1 = fmaxf(m1, __shfl_xor(m1, 32));
            float w10 = __expf(sv1.x - m1), w11 = __expf(sv1.y - m1);
            float w12 = __expf(sv1.z - m1), w13 = __expf(sv1.w - m1);
            float t1 = w10 + w11 + w12 + w13;
            t1 += __shfl_xor(t1, 16);
            t1 += __shfl_xor(t1, 32);
            const float inv1 = 1.0f / t1;

            w00 *= s00; w01 *= s01; w02 *= s02; w03 *= s03;
            w10 *= s10; w11 *= s11; w12 *= s12; w13 *= s13;

            float B0 = w00 + w01 + w02 + w03;   // bias term (feature-indep)
            float B1 = w10 + w11 + w12 + w13;

            f32x4 acc0 = {0,0,0,0}, acc1 = {0,0,0,0};
            dq_acc(p00, w00, acc0); dq_acc(p01, w01, acc0);
            dq_acc(p02, w02, acc0); dq_acc(p03, w03, acc0);
            dq_acc(p10, w10, acc1); dq_acc(p11, w11, acc1);
            dq_acc(p12, w12, acc1); dq_acc(p13, w13, acc1);

            B0 += __shfl_xor(B0, 16);  B0 += __shfl_xor(B0, 32);
            B1 += __shfl_xor(B1, 16);  B1 += __shfl_xor(B1, 32);
            acc0.x += __shfl_xor(acc0.x, 16);  acc0.x += __shfl_xor(acc0.x, 32);
            acc0.y += __shfl_xor(acc0.y, 16);  acc0.y += __shfl_xor(acc0.y, 32);
            acc0.z += __shfl_xor(acc0.z, 16);  acc0.z += __shfl_xor(acc0.z, 32);
            acc0.w += __shfl_xor(acc0.w, 16);  acc0.w += __shfl_xor(acc0.w, 32);
            acc1.x += __shfl_xor(acc1.x, 16);  acc1.x += __shfl_xor(acc1.x, 32);
            acc1.y += __shfl_xor(acc1.y, 16);  acc1.y += __shfl_xor(acc1.y, 32);
            acc1.z += __shfl_xor(acc1.z, 16);  acc1.z += __shfl_xor(acc1.z, 32);
            acc1.w += __shfl_xor(acc1.w, 16);  acc1.w += __shfl_xor(acc1.w, 32);

            const float b0 = 128.0f * B0, b1 = 128.0f * B1;
            acc0.x = (acc0.x - b0) * inv0;  acc0.y = (acc0.y - b0) * inv0;
            acc0.z = (acc0.z - b0) * inv0;  acc0.w = (acc0.w - b0) * inv0;
            acc1.x = (acc1.x - b1) * inv1;  acc1.y = (acc1.y - b1) * inv1;
            acc1.z = (acc1.z - b1) * inv1;  acc1.w = (acc1.w - b1) * inv1;

            if (q == 0) {
                __builtin_nontemporal_store(acc0,
                    (f32x4*)(out + ((long long)wid0 << 6)) + f4);
            } else if (q == 1) {
                __builtin_nontemporal_store(acc1,
                    (f32x4*)(out + ((long long)(wid0 + 1) << 6)) + f4);
            }
            return;
        }
    }

    for (int n = 0; n < 2; ++n) {
        const int node = wid0 + n;
        if (node >= num_nodes) break;
        node_generic(row_ptr_v, col_idx_v, scores, values, out, node, lane, idx64);
    }
}

// =================== fused cooperative kernel (LDS-free) ===================
__global__ __launch_bounds__(256, 4) void fused_gat_kernel(
    const void* __restrict__ row_ptr_v,
    const void* __restrict__ col_idx_v,
    const float* __restrict__ scores,
    const float* __restrict__ values,
    int* __restrict__ vq,
    float* __restrict__ scale,
    float* __restrict__ out,
    int num_nodes, long long num_edges, int num_rows)
{
    cg::grid_group grid = cg::this_grid();

    const int lane  = threadIdx.x & 63;
    const int q     = lane >> 4;
    const int f4    = lane & 15;
    const int gwave = (blockIdx.x << 2) + (threadIdx.x >> 6);
    const int nwv   = NB * 4;

    const int* rp32 = (const int*)row_ptr_v;
    const bool idx64 = (rp32[1] == 0);

    // phase 0: quant (grid-strided, 16 rows per wave-iteration).
    // FIX vs R12: group offset is +q (rows 16w + q + 4i), NOT +4q.
    for (int rb = gwave * 16; rb < num_rows; rb += nwv * 16)
        quant_rows16(values, vq, scale, num_rows, rb + q, f4);

    __threadfence();   // device-scope release of vq/scale (cross-XCD)
    grid.sync();
    __threadfence();   // acquire side

    // phase 1: aggregation (grid-strided over node pairs)
    const int pairs = (num_nodes + 1) >> 1;
    for (int p = gwave; p < pairs; p += nwv)
        pair_body(rp32, row_ptr_v, col_idx_v, scores, vq, scale, values, out,
                  num_nodes, num_edges, idx64, 2 * p, lane, q, f4);
}

// =================== standalone two-kernel fallback (R10 path) ===================
__global__ __launch_bounds__(256) void quant_kernel(
    const float* __restrict__ values, int* __restrict__ vq,
    float* __restrict__ scale, int num_rows)
{
    const int lane = threadIdx.x & 63;
    const int wave = blockIdx.x * 4 + (threadIdx.x >> 6);
    // R10-proven mapping: rows 16*wave + (lane>>4) + 4i
    quant_rows16(values, vq, scale, num_rows,
                 wave * 16 + (lane >> 4), lane & 15);
}

__global__ __launch_bounds__(256) void gat_agg_u8_kernel(
    const void* __restrict__ row_ptr_v, const void* __restrict__ col_idx_v,
    const float* __restrict__ scores, const int* __restrict__ vq,
    const float* __restrict__ scale, const float* __restrict__ values,
    float* __restrict__ out, int num_nodes, long long num_edges)
{
    const int wv   = blockIdx.x * 4 + (threadIdx.x >> 6);
    const int lane = threadIdx.x & 63;
    const int wid0 = wv * 2;
    if (wid0 >= num_nodes) return;
    const int* rp32 = (const int*)row_ptr_v;
    const bool idx64 = (rp32[1] == 0);
    pair_body(rp32, row_ptr_v, col_idx_v, scores, vq, scale, values, out,
              num_nodes, num_edges, idx64, wid0, lane, lane >> 4, lane & 15);
}

__global__ __launch_bounds__(256) void gat_agg_fp32_kernel(
    const void* __restrict__ row_ptr_v, const void* __restrict__ col_idx_v,
    const float* __restrict__ scores, const float* __restrict__ values,
    float* __restrict__ out, int num_nodes)
{
    const int wid  = blockIdx.x * 4 + (threadIdx.x >> 6);
    const int lane = threadIdx.x & 63;
    if (wid >= num_nodes) return;
    const int* rp32 = (const int*)row_ptr_v;
    const bool idx64 = (rp32[1] == 0);
    node_generic(row_ptr_v, col_idx_v, scores, values, out, wid, lane, idx64);
}

extern "C" void kernel_launch(void* const* d_in, const int* in_sizes, int n_in,
                              void* d_out, int out_size, void* d_ws, size_t ws_size,
                              hipStream_t stream) {
    const void*  row_ptr = d_in[0];
    const void*  col_idx = d_in[1];
    const float* scores  = (const float*)d_in[2];
    const float* values  = (const float*)d_in[3];
    float*       out     = (float*)d_out;

    const int num_nodes = in_sizes[0] - 1;          // 100000
    long long num_edges = (long long)in_sizes[2];
    const long long nvals = (long long)in_sizes[3]; // rows * 64
    int num_rows = (int)(nvals / FEAT);

    const size_t scale_off = ((size_t)nvals + 511) & ~(size_t)511;  // u8 vq bytes
    const size_t need = scale_off + (size_t)num_rows * sizeof(float);

    if (ws_size < need) {
        const int blocks = (num_nodes + 3) / 4;
        hipLaunchKernelGGL(gat_agg_fp32_kernel, dim3(blocks), dim3(256), 0, stream,
                           row_ptr, col_idx, scores, values, out, num_nodes);
        return;
    }

    int*   vq    = (int*)d_ws;
    float* scale = (float*)((char*)d_ws + scale_off);

    void* args[10];
    args[0] = (void*)&row_ptr;
    args[1] = (void*)&col_idx;
    args[2] = (void*)&scores;
    args[3] = (void*)&values;
    args[4] = (void*)&vq;
    args[5] = (void*)&scale;
    args[6] = (void*)&out;
    args[7] = (void*)&num_nodes;
    args[8] = (void*)&num_edges;
    args[9] = (void*)&num_rows;

    hipError_t err = hipLaunchCooperativeKernel((const void*)fused_gat_kernel,
                                                dim3(NB), dim3(256), args, 0, stream);
    if (err != hipSuccess) {
        // deterministic fallback: identical math via the R10 two-kernel path
        const int qblocks = (num_rows + 63) / 64;   // 64 rows/block
        hipLaunchKernelGGL(quant_kernel, dim3(qblocks), dim3(256), 0, stream,
                           values, vq, scale, num_rows);
        const int blocks = (num_nodes + 7) / 8;     // 4 waves x 2 nodes
        hipLaunchKernelGGL(gat_agg_u8_kernel, dim3(blocks), dim3(256), 0, stream,
                           row_ptr, col_idx, scores, vq, scale, values, out,
                           num_nodes, num_edges);
    }
}

// Round 15
// 49.076 us; speedup vs baseline: 5.4385x; 5.4385x over previous
//
#include <hip/hip_runtime.h>
#include <math.h>

#define FEAT 64

typedef float f32x4 __attribute__((ext_vector_type(4)));
typedef int   i32x4 __attribute__((ext_vector_type(4)));

// dequant-accumulate one packed word (4 biased-uint8 feats) into acc.
// (float)(u & 255) etc. fold to v_cvt_f32_ubyte{0..3} (1 instr per elem).
__device__ __forceinline__ void dq_acc(int p, float wk, f32x4& acc) {
    unsigned up = (unsigned)p;
    acc.x = fmaf(wk, (float)(up & 255u),         acc.x);
    acc.y = fmaf(wk, (float)((up >> 8) & 255u),  acc.y);
    acc.z = fmaf(wk, (float)((up >> 16) & 255u), acc.z);
    acc.w = fmaf(wk, (float)(up >> 24),          acc.w);
}

// ---------- pre-pass: per-row biased-uint8 quantization (ONE-SHOT) ----------
// 16 rows per block, 4 rows per wave, no loop: 25K waves of
// {1 f32x4 load, 4 group shuffles, 1 packed store} -> pure TLP, BW-bound.
// Plain stores to d_ws (R5 lesson: no nt stores to device-consumed buffers).
__global__ __launch_bounds__(256) void quant_kernel(
    const float* __restrict__ values,
    int* __restrict__ vq,          // 16 packed dwords per row (64B)
    float* __restrict__ scale,
    int num_rows)
{
    const int lane = threadIdx.x & 63;
    const int g    = lane >> 4;
    const int f4   = lane & 15;
    const int wave = blockIdx.x * 4 + (threadIdx.x >> 6);
    const int row  = wave * 4 + g;

    f32x4 v = {0.0f, 0.0f, 0.0f, 0.0f};
    if (row < num_rows)
        v = __builtin_nontemporal_load(
                (const f32x4*)(values + (long long)row * FEAT) + f4);

    float a = fmaxf(fmaxf(fabsf(v.x), fabsf(v.y)),
                    fmaxf(fabsf(v.z), fabsf(v.w)));
    a = fmaxf(a, __shfl_xor(a, 1));
    a = fmaxf(a, __shfl_xor(a, 2));
    a = fmaxf(a, __shfl_xor(a, 4));
    a = fmaxf(a, __shfl_xor(a, 8));

    if (row < num_rows) {
        const float inv = (a > 0.0f) ? 127.0f / a : 0.0f;
        int q0 = (int)rintf(v.x * inv) + 128;
        int q1 = (int)rintf(v.y * inv) + 128;
        int q2 = (int)rintf(v.z * inv) + 128;
        int q3 = (int)rintf(v.w * inv) + 128;
        vq[((unsigned)row << 4) + f4] = q0 | (q1 << 8) | (q2 << 16) | (q3 << 24);
        if (f4 == 0) scale[row] = a * (1.0f / 127.0f);
    }
}

// generic per-node fallback (any degree, either index width, fp32 values)
__device__ __noinline__ void node_generic(
    const void* row_ptr_v, const void* col_idx_v, const float* scores,
    const float* values, float* out, int node, int lane, bool idx64)
{
    const int* rp32 = (const int*)row_ptr_v;
    long long start, end;
    if (idx64) {
        const long long* rp = (const long long*)row_ptr_v;
        start = rp[node]; end = rp[node + 1];
    } else {
        start = (long long)rp32[node]; end = (long long)rp32[node + 1];
    }
    float m = -INFINITY;
    for (long long e = start; e < end; ++e) m = fmaxf(m, scores[e]);
    float sum = 0.0f;
    for (long long e = start; e < end; ++e) sum += __expf(scores[e] - m);
    const float invs = (sum > 0.0f) ? 1.0f / sum : 0.0f;
    float acc = 0.0f;
    for (long long e = start; e < end; ++e) {
        long long c = idx64 ? ((const long long*)col_idx_v)[e]
                            : (long long)((const int*)col_idx_v)[e];
        acc += __expf(scores[e] - m) * values[c * FEAT + lane];
    }
    out[(long long)node * FEAT + lane] = acc * invs;
}

// ---------- main: TWO nodes per wave, speculative gather issue (R10) ----------
// lane = (q = lane>>4 quadrant, f4 = lane&15 dword slot).
// vq/scale gathers depend only on cv (valid node ids by construction), so
// they are issued BEFORE the uni row_ptr check resolves.
__global__ __launch_bounds__(256) void gat_agg_u8_kernel(
    const void* __restrict__ row_ptr_v,
    const void* __restrict__ col_idx_v,
    const float* __restrict__ scores,
    const int* __restrict__ vq,
    const float* __restrict__ scale,
    const float* __restrict__ values,   // fp32 fallback
    float* __restrict__ out,
    int num_nodes, long long num_edges)
{
    const int wv   = blockIdx.x * 4 + (threadIdx.x >> 6);
    const int lane = threadIdx.x & 63;
    const int wid0 = wv * 2;
    if (wid0 >= num_nodes) return;

    const int* rp32 = (const int*)row_ptr_v;
    const bool idx64 = (rp32[1] == 0);

    const int q  = lane >> 4;
    const int f4 = lane & 15;

    const long long base = (long long)wid0 * 16;
    const bool inb = (wid0 + 2 <= num_nodes) && (base + 32 <= num_edges);

    if (inb && !idx64) {
        const int b16 = wid0 * 16;
        const int r0 = rp32[wid0], r1 = rp32[wid0 + 1], r2 = rp32[wid0 + 2];

        const float* sb = scores + base;
        const int*   cb = (const int*)col_idx_v + base;
        f32x4 sv0 = __builtin_nontemporal_load((const f32x4*)sb + q);
        f32x4 sv1 = __builtin_nontemporal_load((const f32x4*)(sb + 16) + q);
        i32x4 cv0 = __builtin_nontemporal_load((const i32x4*)cb + q);
        i32x4 cv1 = __builtin_nontemporal_load((const i32x4*)(cb + 16) + q);

        // speculative: all 8 row gathers + 8 scale loads before uni resolves
        int p00 = vq[((unsigned)cv0.x << 4) + f4];
        int p01 = vq[((unsigned)cv0.y << 4) + f4];
        int p02 = vq[((unsigned)cv0.z << 4) + f4];
        int p03 = vq[((unsigned)cv0.w << 4) + f4];
        int p10 = vq[((unsigned)cv1.x << 4) + f4];
        int p11 = vq[((unsigned)cv1.y << 4) + f4];
        int p12 = vq[((unsigned)cv1.z << 4) + f4];
        int p13 = vq[((unsigned)cv1.w << 4) + f4];
        float s00 = scale[cv0.x], s01 = scale[cv0.y];
        float s02 = scale[cv0.z], s03 = scale[cv0.w];
        float s10 = scale[cv1.x], s11 = scale[cv1.y];
        float s12 = scale[cv1.z], s13 = scale[cv1.w];

        const bool uni = (r0 == b16) && (r1 == b16 + 16) && (r2 == b16 + 32);
        if (uni) {
            float m0 = fmaxf(fmaxf(sv0.x, sv0.y), fmaxf(sv0.z, sv0.w));
            m0 = fmaxf(m0, __shfl_xor(m0, 16));
            m0 = fmaxf(m0, __shfl_xor(m0, 32));
            float w00 = __expf(sv0.x - m0), w01 = __expf(sv0.y - m0);
            float w02 = __expf(sv0.z - m0), w03 = __expf(sv0.w - m0);
            float t0 = w00 + w01 + w02 + w03;
            t0 += __shfl_xor(t0, 16);
            t0 += __shfl_xor(t0, 32);
            const float inv0 = 1.0f / t0;

            float m1 = fmaxf(fmaxf(sv1.x, sv1.y), fmaxf(sv1.z, sv1.w));
            m1 = fmaxf(m1, __shfl_xor(m1, 16));
            m1 = fmaxf(m1, __shfl_xor(m1, 32));
            float w10 = __expf(sv1.x - m1), w11 = __expf(sv1.y - m1);
            float w12 = __expf(sv1.z - m1), w13 = __expf(sv1.w - m1);
            float t1 = w10 + w11 + w12 + w13;
            t1 += __shfl_xor(t1, 16);
            t1 += __shfl_xor(t1, 32);
            const float inv1 = 1.0f / t1;

            w00 *= s00; w01 *= s01; w02 *= s02; w03 *= s03;
            w10 *= s10; w11 *= s11; w12 *= s12; w13 *= s13;

            float B0 = w00 + w01 + w02 + w03;   // bias term (feature-indep)
            float B1 = w10 + w11 + w12 + w13;

            f32x4 acc0 = {0,0,0,0}, acc1 = {0,0,0,0};
            dq_acc(p00, w00, acc0); dq_acc(p01, w01, acc0);
            dq_acc(p02, w02, acc0); dq_acc(p03, w03, acc0);
            dq_acc(p10, w10, acc1); dq_acc(p11, w11, acc1);
            dq_acc(p12, w12, acc1); dq_acc(p13, w13, acc1);

            B0 += __shfl_xor(B0, 16);  B0 += __shfl_xor(B0, 32);
            B1 += __shfl_xor(B1, 16);  B1 += __shfl_xor(B1, 32);
            acc0.x += __shfl_xor(acc0.x, 16);  acc0.x += __shfl_xor(acc0.x, 32);
            acc0.y += __shfl_xor(acc0.y, 16);  acc0.y += __shfl_xor(acc0.y, 32);
            acc0.z += __shfl_xor(acc0.z, 16);  acc0.z += __shfl_xor(acc0.z, 32);
            acc0.w += __shfl_xor(acc0.w, 16);  acc0.w += __shfl_xor(acc0.w, 32);
            acc1.x += __shfl_xor(acc1.x, 16);  acc1.x += __shfl_xor(acc1.x, 32);
            acc1.y += __shfl_xor(acc1.y, 16);  acc1.y += __shfl_xor(acc1.y, 32);
            acc1.z += __shfl_xor(acc1.z, 16);  acc1.z += __shfl_xor(acc1.z, 32);
            acc1.w += __shfl_xor(acc1.w, 16);  acc1.w += __shfl_xor(acc1.w, 32);

            const float b0 = 128.0f * B0, b1 = 128.0f * B1;
            acc0.x = (acc0.x - b0) * inv0;  acc0.y = (acc0.y - b0) * inv0;
            acc0.z = (acc0.z - b0) * inv0;  acc0.w = (acc0.w - b0) * inv0;
            acc1.x = (acc1.x - b1) * inv1;  acc1.y = (acc1.y - b1) * inv1;
            acc1.z = (acc1.z - b1) * inv1;  acc1.w = (acc1.w - b1) * inv1;

            if (q == 0) {
                __builtin_nontemporal_store(acc0,
                    (f32x4*)(out + ((long long)wid0 << 6)) + f4);
            } else if (q == 1) {
                __builtin_nontemporal_store(acc1,
                    (f32x4*)(out + ((long long)(wid0 + 1) << 6)) + f4);
            }
            return;
        }
    }

    // fallback: per-node generic
    for (int n = 0; n < 2; ++n) {
        const int node = wid0 + n;
        if (node >= num_nodes) break;
        node_generic(row_ptr_v, col_idx_v, scores, values, out, node, lane, idx64);
    }
}

// fp32-only variant (workspace too small)
__global__ __launch_bounds__(256) void gat_agg_fp32_kernel(
    const void* __restrict__ row_ptr_v, const void* __restrict__ col_idx_v,
    const float* __restrict__ scores, const float* __restrict__ values,
    float* __restrict__ out, int num_nodes)
{
    const int wid  = blockIdx.x * 4 + (threadIdx.x >> 6);
    const int lane = threadIdx.x & 63;
    if (wid >= num_nodes) return;
    const int* rp32 = (const int*)row_ptr_v;
    const bool idx64 = (rp32[1] == 0);
    node_generic(row_ptr_v, col_idx_v, scores, values, out, wid, lane, idx64);
}

extern "C" void kernel_launch(void* const* d_in, const int* in_sizes, int n_in,
                              void* d_out, int out_size, void* d_ws, size_t ws_size,
                              hipStream_t stream) {
    const void*  row_ptr = d_in[0];
    const void*  col_idx = d_in[1];
    const float* scores  = (const float*)d_in[2];
    const float* values  = (const float*)d_in[3];
    float*       out     = (float*)d_out;

    const int num_nodes = in_sizes[0] - 1;          // 100000
    const long long num_edges = (long long)in_sizes[2];
    const long long nvals = (long long)in_sizes[3]; // rows * 64
    const int num_rows = (int)(nvals / FEAT);

    const size_t scale_off = ((size_t)nvals + 511) & ~(size_t)511;  // u8 vq bytes
    const size_t need = scale_off + (size_t)num_rows * sizeof(float);

    if (ws_size >= need) {
        int*   vq    = (int*)d_ws;
        float* scale = (float*)((char*)d_ws + scale_off);

        const int qblocks = (num_rows + 15) / 16;   // one-shot: 16 rows/block
        hipLaunchKernelGGL(quant_kernel, dim3(qblocks), dim3(256), 0, stream,
                           values, vq, scale, num_rows);

        const int nodes_per_block = 4 * 2;          // 4 waves x 2 nodes
        const int blocks = (num_nodes + nodes_per_block - 1) / nodes_per_block;
        hipLaunchKernelGGL(gat_agg_u8_kernel, dim3(blocks), dim3(256), 0, stream,
                           row_ptr, col_idx, scores, vq, scale, values, out,
                           num_nodes, num_edges);
    } else {
        const int blocks = (num_nodes + 3) / 4;
        hipLaunchKernelGGL(gat_agg_fp32_kernel, dim3(blocks), dim3(256), 0, stream,
                           row_ptr, col_idx, scores, values, out, num_nodes);
    }
}